// Round 7
// baseline (504.728 us; speedup 1.0000x reference)
//
#include <hip/hip_runtime.h>

// Problem constants (match reference)
constexpr int N_OP    = 100000;
constexpr int N_M     = 2000;
constexpr int IN_DIM  = 64;
constexpr int OUT_DIM = 128;
constexpr int E_SEQ_N  = 100000;
constexpr int E_OP2M_N = 2000000;

// Counting-sort partitioning for the machine axis
constexpr int W_BLK     = 512;                       // partitions of the edge list
constexpr int CHUNK     = (E_OP2M_N + W_BLK - 1) / W_BLK;  // 3907
constexpr int SEQ_CHUNK = (E_SEQ_N + W_BLK - 1) / W_BLK;   // 196

// S layout: scan over [degOp(100000) | degSeq(100000) | trailing 0]
constexpr int OFF_SEQ2 = 100000;
constexpr int SCAN_N2  = 200001;

__device__ __forceinline__ float bf2f(unsigned short h) {
  return __uint_as_float((unsigned)h << 16);
}

// ---------------- Projection: Y[nrows,128] = X[nrows,64] @ W[64,128] + b ----------------
// Also emits a bf16 (RNE) copy Yh for the bandwidth-bound gathers.
__global__ __launch_bounds__(256) void proj_kernel(
    const float* __restrict__ X, const float* __restrict__ W,
    const float* __restrict__ b, float* __restrict__ Y,
    unsigned short* __restrict__ Yh, int nrows) {
  __shared__ float Ws[IN_DIM * OUT_DIM];   // 32 KB
  __shared__ float bs[OUT_DIM];
  __shared__ float Xs[16 * IN_DIM];        // 4 KB
  const int t = threadIdx.x;
  for (int i = t; i < IN_DIM * OUT_DIM; i += 256) Ws[i] = W[i];
  if (t < OUT_DIM) bs[t] = b[t];
  const int row0 = blockIdx.x * 16;
  const int nr = min(16, nrows - row0);
  for (int i = t; i < nr * IN_DIM; i += 256) Xs[i] = X[(size_t)row0 * IN_DIM + i];
  __syncthreads();
  const int c = t & 127;
  #pragma unroll
  for (int k = 0; k < 8; ++k) {
    const int o = t + k * 256;
    const int r = o >> 7;
    if (r >= nr) break;
    float acc = bs[c];
    #pragma unroll
    for (int j = 0; j < IN_DIM; ++j)
      acc += Xs[r * IN_DIM + j] * Ws[j * OUT_DIM + c];
    const size_t idx = (size_t)(row0 + r) * OUT_DIM + c;
    Y[idx] = acc;
    unsigned u = __float_as_uint(acc);
    u += 0x7fffu + ((u >> 16) & 1u);      // round-to-nearest-even bf16
    Yh[idx] = (unsigned short)(u >> 16);
  }
}

// ---------------- Phase A: per-block m-histogram + op/seq degree atomics ----------------
__global__ __launch_bounds__(512) void histA_kernel(
    const int* __restrict__ Eseq, const int* __restrict__ Eop2m,
    int* __restrict__ H, int* __restrict__ degOp, int* __restrict__ degSeq) {
  __shared__ int h[N_M];   // 8 KB
  for (int i = threadIdx.x; i < N_M; i += 512) h[i] = 0;
  __syncthreads();
  const int w = blockIdx.x;
  const int e0 = w * CHUNK, e1 = min(E_OP2M_N, e0 + CHUNK);
  for (int e = e0 + threadIdx.x; e < e1; e += 512) {
    atomicAdd(&degOp[Eop2m[e]], 1);
    atomicAdd(&h[Eop2m[E_OP2M_N + e]], 1);
  }
  const int s0 = w * SEQ_CHUNK, s1 = min(E_SEQ_N, s0 + SEQ_CHUNK);
  for (int e = s0 + threadIdx.x; e < s1; e += 512)
    atomicAdd(&degSeq[Eseq[E_SEQ_N + e]], 1);
  __syncthreads();
  for (int i = threadIdx.x; i < N_M; i += 512) H[w * N_M + i] = h[i];
}

// ---------------- Phase B: exclusive column scan of H; degM = column sums ----------------
__global__ __launch_bounds__(512) void colscan_kernel(int* __restrict__ H, int* __restrict__ degM) {
  __shared__ int s[W_BLK];
  const int m = blockIdx.x;
  const int t = threadIdx.x;
  const int v = H[t * N_M + m];
  s[t] = v;
  __syncthreads();
  for (int d = 1; d < W_BLK; d <<= 1) {
    const int x = s[t];
    const int y = (t >= d) ? s[t - d] : 0;
    __syncthreads();
    s[t] = x + y;
    __syncthreads();
  }
  H[t * N_M + m] = s[t] - v;           // exclusive offset of block t within machine m
  if (t == W_BLK - 1) degM[m] = s[W_BLK - 1];
}

// ---------------- baseM: exclusive scan of degM (2000 elems, 1 block) ----------------
__global__ __launch_bounds__(256) void scanM_kernel(
    const int* __restrict__ degM, int* __restrict__ baseM) {
  __shared__ int s[256];
  const int t = threadIdx.x;
  int v[8];
  int sum = 0;
  #pragma unroll
  for (int k = 0; k < 8; ++k) {
    const int i = t * 8 + k;
    v[k] = (i < N_M) ? degM[i] : 0;
    sum += v[k];
  }
  s[t] = sum;
  __syncthreads();
  for (int d = 1; d < 256; d <<= 1) {
    const int x = s[t];
    const int y = (t >= d) ? s[t - d] : 0;
    __syncthreads();
    s[t] = x + y;
    __syncthreads();
  }
  int run = s[t] - sum;
  #pragma unroll
  for (int k = 0; k < 8; ++k) {
    const int i = t * 8 + k;
    if (i < N_M) baseM[i] = run;
    run += v[k];
  }
}

// ---------------- Hierarchical exclusive scan over [degOp|degSeq] ----------------
__global__ __launch_bounds__(256) void scanA_kernel(
    const int* __restrict__ in, int* __restrict__ out, int* __restrict__ blockSums, int n) {
  __shared__ int s[256];
  const int base = blockIdx.x * 1024 + threadIdx.x * 4;
  int v[4];
  #pragma unroll
  for (int k = 0; k < 4; ++k) v[k] = (base + k < n) ? in[base + k] : 0;
  const int tsum = v[0] + v[1] + v[2] + v[3];
  s[threadIdx.x] = tsum;
  __syncthreads();
  for (int d = 1; d < 256; d <<= 1) {
    const int x = s[threadIdx.x];
    const int y = (threadIdx.x >= d) ? s[threadIdx.x - d] : 0;
    __syncthreads();
    s[threadIdx.x] = x + y;
    __syncthreads();
  }
  int run = s[threadIdx.x] - tsum;
  if (threadIdx.x == 255) blockSums[blockIdx.x] = s[255];
  #pragma unroll
  for (int k = 0; k < 4; ++k) {
    if (base + k < n) out[base + k] = run;
    run += v[k];
  }
}

__global__ __launch_bounds__(256) void scanB_kernel(int* __restrict__ bs, int nb) {
  __shared__ int s[256];
  const int t = threadIdx.x;
  const int v = (t < nb) ? bs[t] : 0;
  s[t] = v;
  __syncthreads();
  for (int d = 1; d < 256; d <<= 1) {
    const int x = s[t];
    const int y = (t >= d) ? s[t - d] : 0;
    __syncthreads();
    s[t] = x + y;
    __syncthreads();
  }
  if (t < nb) bs[t] = s[t] - v;
}

__global__ __launch_bounds__(256) void scanC_kernel(
    int* __restrict__ out, const int* __restrict__ bs, int n) {
  const int base = blockIdx.x * 1024 + threadIdx.x * 4;
  const int add = bs[blockIdx.x];
  #pragma unroll
  for (int k = 0; k < 4; ++k)
    if (base + k < n) out[base + k] += add;
}

// ---------------- mL fill via counting-sort offsets (LDS cursors only) ----------------
__global__ __launch_bounds__(512) void fill_m_kernel(
    const int* __restrict__ Eop2m, const int* __restrict__ H, const int* __restrict__ baseM,
    int* __restrict__ mL) {
  __shared__ int lcur[N_M];   // 8 KB
  for (int i = threadIdx.x; i < N_M; i += 512) lcur[i] = 0;
  __syncthreads();
  const int w = blockIdx.x;
  const int base = w * N_M;
  const int e0 = w * CHUNK, e1 = min(E_OP2M_N, e0 + CHUNK);
  for (int e = e0 + threadIdx.x; e < e1; e += 512) {
    const int op = Eop2m[e];
    const int m  = Eop2m[E_OP2M_N + e];
    mL[baseM[m] + H[base + m] + atomicAdd(&lcur[m], 1)] = op;
  }
}

// ---------------- opL (ushort) + seqL fills via low-contention global cursors ----------------
__global__ __launch_bounds__(256) void fill_opseq_kernel(
    const int* __restrict__ Eseq, const int* __restrict__ Eop2m, const int* __restrict__ S,
    int* __restrict__ curOp, int* __restrict__ curSeq,
    unsigned short* __restrict__ opLu, int* __restrict__ seqL) {
  const int stride = gridDim.x * 256;
  const int i0 = blockIdx.x * 256 + threadIdx.x;
  for (int e = i0; e < E_OP2M_N; e += stride) {
    const int op = Eop2m[e];
    const int m  = Eop2m[E_OP2M_N + e];
    opLu[S[op] + atomicAdd(&curOp[op], 1)] = (unsigned short)m;
  }
  for (int e = i0; e < E_SEQ_N; e += stride) {
    const int src = Eseq[e];
    const int dst = Eseq[E_SEQ_N + e];
    seqL[(S[OFF_SEQ2 + dst] - E_OP2M_N) + atomicAdd(&curSeq[dst], 1)] = src;
  }
}

// ---------------- op output: one wave per op node, fully fused ----------------
// Self row fp32 (residual base); seq + machine gathers bf16.
__global__ __launch_bounds__(256) void op_out_kernel(
    const float* __restrict__ HopProj, const unsigned short* __restrict__ HopProjH,
    const unsigned short* __restrict__ HmProjH,
    const int* __restrict__ S, const unsigned short* __restrict__ opLu,
    const int* __restrict__ seqL, float* __restrict__ out) {
  const int wid = (blockIdx.x * 256 + threadIdx.x) >> 6;
  if (wid >= N_OP) return;
  const int lane = threadIdx.x & 63;
  const int i = wid;
  float2 acc = *reinterpret_cast<const float2*>(HopProj + (size_t)i * OUT_DIM + lane * 2);

  // seq aggregation (mean over incoming seq edges), bf16 rows
  const int s0 = S[OFF_SEQ2 + i] - E_OP2M_N;
  const int s1 = S[OFF_SEQ2 + i + 1] - E_OP2M_N;
  float2 a = make_float2(0.f, 0.f);
  for (int e = s0; e < s1; ++e) {
    const int src = seqL[e];
    const ushort2 h = *reinterpret_cast<const ushort2*>(HopProjH + (size_t)src * OUT_DIM + lane * 2);
    a.x += bf2f(h.x); a.y += bf2f(h.y);
  }
  const float wS = 1.0f / (float)max(s1 - s0, 1);
  acc.x += a.x * wS; acc.y += a.y * wS;

  // machine aggregation (mean of HmProj over incident op2m edges), bf16 rows
  const int o0 = S[i];
  const int o1 = S[i + 1];
  float2 b = make_float2(0.f, 0.f);
  int e = o0;
  for (; e + 4 <= o1; e += 4) {
    const int m0 = opLu[e];
    const int m1 = opLu[e + 1];
    const int m2 = opLu[e + 2];
    const int m3 = opLu[e + 3];
    const ushort2 h0 = *reinterpret_cast<const ushort2*>(HmProjH + (size_t)m0 * OUT_DIM + lane * 2);
    const ushort2 h1 = *reinterpret_cast<const ushort2*>(HmProjH + (size_t)m1 * OUT_DIM + lane * 2);
    const ushort2 h2 = *reinterpret_cast<const ushort2*>(HmProjH + (size_t)m2 * OUT_DIM + lane * 2);
    const ushort2 h3 = *reinterpret_cast<const ushort2*>(HmProjH + (size_t)m3 * OUT_DIM + lane * 2);
    b.x += (bf2f(h0.x) + bf2f(h1.x)) + (bf2f(h2.x) + bf2f(h3.x));
    b.y += (bf2f(h0.y) + bf2f(h1.y)) + (bf2f(h2.y) + bf2f(h3.y));
  }
  for (; e < o1; ++e) {
    const int m0 = opLu[e];
    const ushort2 h0 = *reinterpret_cast<const ushort2*>(HmProjH + (size_t)m0 * OUT_DIM + lane * 2);
    b.x += bf2f(h0.x); b.y += bf2f(h0.y);
  }
  const float wO = 1.0f / (float)max(o1 - o0, 1);
  acc.x = fmaxf(acc.x + b.x * wO, 0.f);
  acc.y = fmaxf(acc.y + b.y * wO, 0.f);
  *reinterpret_cast<float2*>(out + (size_t)i * OUT_DIM + lane * 2) = acc;
}

// ---------------- machine output: bf16 gather (256 B/row), fp32 accumulate ----------------
__global__ __launch_bounds__(512) void m_out_kernel(
    const unsigned short* __restrict__ HopProjH, const float* __restrict__ HmProj,
    const int* __restrict__ mL, const int* __restrict__ baseM, const int* __restrict__ degM,
    float* __restrict__ outM) {
  __shared__ float red[16][129];    // 129 pad: conflict-free column reads in reduce
  const int m = blockIdx.x;
  const int s0 = baseM[m];
  const int deg = degM[m];
  const int c4   = (threadIdx.x & 31) << 2;   // column base 0..124
  const int slot = threadIdx.x >> 5;          // 0..15
  float ax = 0.f, ay = 0.f, az = 0.f, aw = 0.f;
  int e = slot;
  for (; e + 48 < deg; e += 64) {
    const int o0 = mL[s0 + e];
    const int o1 = mL[s0 + e + 16];
    const int o2 = mL[s0 + e + 32];
    const int o3 = mL[s0 + e + 48];
    const ushort4 h0 = *reinterpret_cast<const ushort4*>(HopProjH + (size_t)o0 * OUT_DIM + c4);
    const ushort4 h1 = *reinterpret_cast<const ushort4*>(HopProjH + (size_t)o1 * OUT_DIM + c4);
    const ushort4 h2 = *reinterpret_cast<const ushort4*>(HopProjH + (size_t)o2 * OUT_DIM + c4);
    const ushort4 h3 = *reinterpret_cast<const ushort4*>(HopProjH + (size_t)o3 * OUT_DIM + c4);
    ax += (bf2f(h0.x) + bf2f(h1.x)) + (bf2f(h2.x) + bf2f(h3.x));
    ay += (bf2f(h0.y) + bf2f(h1.y)) + (bf2f(h2.y) + bf2f(h3.y));
    az += (bf2f(h0.z) + bf2f(h1.z)) + (bf2f(h2.z) + bf2f(h3.z));
    aw += (bf2f(h0.w) + bf2f(h1.w)) + (bf2f(h2.w) + bf2f(h3.w));
  }
  for (; e < deg; e += 16) {
    const int o = mL[s0 + e];
    const ushort4 h = *reinterpret_cast<const ushort4*>(HopProjH + (size_t)o * OUT_DIM + c4);
    ax += bf2f(h.x); ay += bf2f(h.y); az += bf2f(h.z); aw += bf2f(h.w);
  }
  red[slot][c4 + 0] = ax;
  red[slot][c4 + 1] = ay;
  red[slot][c4 + 2] = az;
  red[slot][c4 + 3] = aw;
  __syncthreads();
  if (threadIdx.x < 128) {
    const int col = threadIdx.x;
    float s = 0.f;
    #pragma unroll
    for (int k = 0; k < 16; ++k) s += red[k][col];
    const float v = HmProj[m * OUT_DIM + col] + s / (float)max(deg, 1);
    outM[m * OUT_DIM + col] = fmaxf(v, 0.f);
  }
}

extern "C" void kernel_launch(void* const* d_in, const int* in_sizes, int n_in,
                              void* d_out, int out_size, void* d_ws, size_t ws_size,
                              hipStream_t stream) {
  const float* H_op   = (const float*)d_in[0];
  const float* H_m    = (const float*)d_in[1];
  const int*   E_seq  = (const int*)d_in[2];
  const int*   E_op2m = (const int*)d_in[3];
  const float* W_op   = (const float*)d_in[4];
  const float* b_op   = (const float*)d_in[5];
  const float* W_m    = (const float*)d_in[6];
  const float* b_m    = (const float*)d_in[7];
  float* out = (float*)d_out;

  // ---- workspace layout (element offsets, 4B units unless noted) ----
  float* HopProj = (float*)d_ws;                                // 12,800,000
  float* HmProj  = HopProj + (size_t)N_OP * OUT_DIM;            //    256,000
  int*   degOp   = (int*)(HmProj + (size_t)N_M * OUT_DIM);      //    100,000 (zeroed)
  int*   degSeq  = degOp + N_OP;                                //    100,000 (zeroed)
  int*   curOp   = degSeq + N_OP;                               //    100,000 (zeroed)
  int*   curSeq  = curOp + N_OP;                                //    100,000 (zeroed)
  int*   degM    = curSeq + N_OP;                               //      2,048
  int*   baseM   = degM + 2048;                                 //      2,048
  int*   S       = baseM + 2048;                                //    200,704
  int*   bsums   = S + 200704;                                  //        512
  int*   Hh      = bsums + 512;                                 //  1,024,000 (W_BLK * N_M)
  unsigned short* opLu = (unsigned short*)(Hh + (size_t)W_BLK * N_M); // 2,000,000 ushort (1M int)
  int*   mL      = (int*)(opLu + E_OP2M_N);                     //  2,000,000
  int*   seqL    = mL + E_OP2M_N;                               //    100,000
  unsigned short* HopProjH = (unsigned short*)(seqL + E_SEQ_N); // 12,800,000 ushort
  unsigned short* HmProjH  = HopProjH + (size_t)N_OP * OUT_DIM; //    256,000 ushort

  // 1. projections (fp32 + bf16 copies)
  proj_kernel<<<(N_OP + 15) / 16, 256, 0, stream>>>(H_op, W_op, b_op, HopProj, HopProjH, N_OP);
  proj_kernel<<<(N_M + 15) / 16, 256, 0, stream>>>(H_m, W_m, b_m, HmProj, HmProjH, N_M);

  // 2. zero degOp/degSeq/curOp/curSeq (contiguous)
  hipMemsetAsync(degOp, 0, (size_t)4 * N_OP * sizeof(int), stream);

  // 3. machine histograms + op/seq degrees
  histA_kernel<<<W_BLK, 512, 0, stream>>>(E_seq, E_op2m, Hh, degOp, degSeq);

  // 4. column scan of H -> per-block offsets + degM; then baseM
  colscan_kernel<<<N_M, W_BLK, 0, stream>>>(Hh, degM);
  scanM_kernel<<<1, 256, 0, stream>>>(degM, baseM);

  // 5. exclusive scan of [degOp|degSeq] -> S
  const int nScanBlocks = (SCAN_N2 + 1023) / 1024;   // 196
  scanA_kernel<<<nScanBlocks, 256, 0, stream>>>(degOp, S, bsums, SCAN_N2);
  scanB_kernel<<<1, 256, 0, stream>>>(bsums, nScanBlocks);
  scanC_kernel<<<nScanBlocks, 256, 0, stream>>>(S, bsums, SCAN_N2);

  // 6. fill adjacency lists (split: high-occupancy cursor fills + counting-sort mL)
  fill_opseq_kernel<<<2048, 256, 0, stream>>>(E_seq, E_op2m, S, curOp, curSeq, opLu, seqL);
  fill_m_kernel<<<W_BLK, 512, 0, stream>>>(E_op2m, Hh, baseM, mL);

  // 7. outputs
  {
    const long long threads = (long long)N_OP * 64;
    op_out_kernel<<<(int)((threads + 255) / 256), 256, 0, stream>>>(
        HopProj, HopProjH, HmProjH, S, opLu, seqL, out);
  }
  m_out_kernel<<<N_M, 512, 0, stream>>>(HopProjH, HmProj, mL, baseM, degM,
                                        out + (size_t)N_OP * OUT_DIM);
}